// Round 5
// baseline (133.961 us; speedup 1.0000x reference)
//
#include <hip/hip_runtime.h>

// DotProductAttention reduced form (verified rounds 1-4, absmax 0.0156):
//   Qeff[q] = 0.7*Q[q-1] + Q[q] + 0.7*Q[q+1]  (zero pad at edges)
//   out[q]  = softmax_{k <= max(q-1,0)}( Qeff[q]·K[k]/8 + beta[k] ) @ V
// Round 5: 512 blocks x 4 waves (kh half x qh half), heavy-first, 3 blocks/CU
// (LDS 36.9KB, Qeff overlaid on K-buf1). Zero-exposed-latency pipeline: writes ->
// barrier A -> issue t+2 loads -> ds_reads -> compute -> barrier B. Permuted
// key->M-row (S^T C-frag == PV B-frag, P in registers), fixed-max softmax,
// XOR-swizzled K AND V LDS layout (round-4 V was 8-way conflicted).

typedef short bf16x8 __attribute__((ext_vector_type(8)));
typedef float f32x4  __attribute__((ext_vector_type(4)));

constexpr int S_ = 2048;
constexpr int D_ = 64;
constexpr int KSTR = 72;
constexpr float LOG2E = 1.44269504088896341f;
constexpr float KSC = 0.125f * LOG2E;   // 1/sqrt(64), log2 domain

// pack two fp32 -> dword of 2 bf16 (round-half-up), lo in low 16
__device__ __forceinline__ unsigned pk2(float lo, float hi) {
    union { float f; unsigned u; } a, b;
    a.f = lo; b.f = hi;
    return __builtin_amdgcn_perm(b.u + 0x8000u, a.u + 0x8000u, 0x07060302u);
}

__global__ __launch_bounds__(256, 3)
void attn5(const float* __restrict__ Q, const float* __restrict__ K,
           const float* __restrict__ V, const float* __restrict__ beta,
           float* __restrict__ out)
{
    // ushort layout: K0 @0, K1/Qs @4608, V0 @9216, V1 @13824 (each 64x72) = 36864 B.
    // Epilogue overlay at base: opub 64x68 floats + lred[64].
    __shared__ __align__(16) unsigned short smem[18432];

    const int bid = blockIdx.x;
    const int bh = bid & 15;              // XCD bid&7 sees heads {x, x+8} only
    const int qt = 31 - (bid >> 4);       // heavy blocks dispatched first
    const int q0 = qt << 6;
    const int nt = qt + 1;

    const float* Qh = Q + bh * (S_ * D_);
    const float* Kh = K + bh * (S_ * D_);
    const float* Vh = V + bh * (S_ * D_);

    const int t = threadIdx.x, lane = t & 63;
    const int wv = t >> 6, kh = wv & 1, qh = wv >> 1;
    const int n_l = lane & 15, qd = lane >> 4;

    // ---- staging indices ----
    const int rk = t >> 2, c0 = (t & 3) << 1;                 // K: row, 2 chunks
    const int kw0 = rk * KSTR + ((c0 + (rk >> 3)) & 7) * 8;   // swizzled slots
    const int kw1 = rk * KSTR + ((c0 + 1 + (rk >> 3)) & 7) * 8;
    const int k2 = (t & 31) << 1, dg = t >> 5;                // V^T: key pair, d group
    const int vw = (dg << 3) * KSTR + ((((k2 >> 3) + dg) & 7) << 3) + (k2 & 7);

    int aoff[2][2];
    {
        const int krb = (kh << 5) + ((n_l >> 2) << 3) + (n_l & 3);  // permuted key->M-row
        #pragma unroll
        for (int mb = 0; mb < 2; ++mb) {
            const int krow = krb + (mb << 2);
            #pragma unroll
            for (int h = 0; h < 2; ++h)
                aoff[mb][h] = krow * KSTR + ((((h << 2) + qd) + (krow >> 3)) & 7) * 8;
        }
    }
    int voff[4];
    #pragma unroll
    for (int mb = 0; mb < 4; ++mb) {
        const int d = (mb << 4) + n_l;
        voff[mb] = d * KSTR + ((((kh << 2) + qd) + (d >> 3)) & 7) * 8;
    }

    // ---- issue tile-0 global loads ----
    float kr[16], vr[16];
    const float* kgp = Kh + rk * D_ + (c0 << 3);
    const float* vgp = Vh + k2 * D_ + (dg << 3);
    #pragma unroll
    for (int i = 0; i < 4; ++i) *(float4*)&kr[4 * i] = *(const float4*)(kgp + 4 * i);
    *(float4*)&vr[0]  = *(const float4*)(vgp);
    *(float4*)&vr[4]  = *(const float4*)(vgp + 4);
    *(float4*)&vr[8]  = *(const float4*)(vgp + D_);
    *(float4*)&vr[12] = *(const float4*)(vgp + D_ + 4);

    // ---- stage Qeff -> Qs (overlay on K1; K1 first written at it=0 for tile 1) ----
    unsigned short* Qs = &smem[4608];
    {
        const int r = t >> 2, d16 = (t & 3) << 4;
        const int q = q0 + r;
        const float wp = (q > 0) ? 0.7f : 0.0f;
        const float wn = (q + 1 < S_) ? 0.7f : 0.0f;
        const float* qc = Qh + q * D_ + d16;
        const float* qp = qc - ((q > 0) ? D_ : 0);
        const float* qn = qc + ((q + 1 < S_) ? D_ : 0);
        unsigned pkd[8];
        #pragma unroll
        for (int i = 0; i < 4; ++i) {
            float4 c4 = *(const float4*)(qc + 4 * i);
            float4 p4 = *(const float4*)(qp + 4 * i);
            float4 n4 = *(const float4*)(qn + 4 * i);
            float e0 = fmaf(wn, n4.x, fmaf(wp, p4.x, c4.x));
            float e1 = fmaf(wn, n4.y, fmaf(wp, p4.y, c4.y));
            float e2 = fmaf(wn, n4.z, fmaf(wp, p4.z, c4.z));
            float e3 = fmaf(wn, n4.w, fmaf(wp, p4.w, c4.w));
            pkd[2 * i]     = pk2(e0, e1);
            pkd[2 * i + 1] = pk2(e2, e3);
        }
        *(uint4*)&Qs[r * KSTR + d16]     = make_uint4(pkd[0], pkd[1], pkd[2], pkd[3]);
        *(uint4*)&Qs[r * KSTR + d16 + 8] = make_uint4(pkd[4], pkd[5], pkd[6], pkd[7]);
    }
    __syncthreads();

    // qb B-fragments (live for the whole loop)
    bf16x8 qb[2][2];
    #pragma unroll
    for (int ng = 0; ng < 2; ++ng) {
        const int row = (qh << 5) + (ng << 4) + n_l;
        qb[ng][0] = *(const bf16x8*)&Qs[row * KSTR + (qd << 3)];
        qb[ng][1] = *(const bf16x8*)&Qs[row * KSTR + 32 + (qd << 3)];
    }

    // write tile 0 -> K0/V0
    {
        unsigned pkd[8];
        #pragma unroll
        for (int i = 0; i < 8; ++i) pkd[i] = pk2(kr[2 * i], kr[2 * i + 1]);
        *(uint4*)&smem[kw0] = make_uint4(pkd[0], pkd[1], pkd[2], pkd[3]);
        *(uint4*)&smem[kw1] = make_uint4(pkd[4], pkd[5], pkd[6], pkd[7]);
        #pragma unroll
        for (int i = 0; i < 8; ++i)
            *(unsigned*)&smem[9216 + vw + i * KSTR] = pk2(vr[i], vr[8 + i]);
    }
    __syncthreads();   // qb landed (all waves), tile-0 writes done; no vm outstanding

    // issue tile-1 loads
    if (nt > 1) {
        #pragma unroll
        for (int i = 0; i < 4; ++i) *(float4*)&kr[4 * i] = *(const float4*)(kgp + 4096 + 4 * i);
        *(float4*)&vr[0]  = *(const float4*)(vgp + 4096);
        *(float4*)&vr[4]  = *(const float4*)(vgp + 4100);
        *(float4*)&vr[8]  = *(const float4*)(vgp + 4096 + D_);
        *(float4*)&vr[12] = *(const float4*)(vgp + 4100 + D_);
    }

    f32x4 o[4][2];
    float l[2] = {0.0f, 0.0f};
    #pragma unroll
    for (int mb = 0; mb < 4; ++mb)
        #pragma unroll
        for (int ng = 0; ng < 2; ++ng) o[mb][ng] = (f32x4){0, 0, 0, 0};

    const int kbase = (kh << 5) + (qd << 3);
    const float* bp = beta + kbase;

    for (int it = 0; it < nt; ++it) {
        const int kcb = (it & 1) ? 4608 : 0;
        const int vcb = (it & 1) ? 13824 : 9216;

        // ---- write tile it+1 (regs loaded >=1 full iter ago) -> other buffers ----
        if (it + 1 < nt) {
            const int kwb = (it & 1) ? 0 : 4608;
            const int vwb = (it & 1) ? 9216 : 13824;
            unsigned pkd[8];
            #pragma unroll
            for (int i = 0; i < 8; ++i) pkd[i] = pk2(kr[2 * i], kr[2 * i + 1]);
            *(uint4*)&smem[kwb + kw0] = make_uint4(pkd[0], pkd[1], pkd[2], pkd[3]);
            *(uint4*)&smem[kwb + kw1] = make_uint4(pkd[4], pkd[5], pkd[6], pkd[7]);
            #pragma unroll
            for (int i = 0; i < 8; ++i)
                *(unsigned*)&smem[vwb + vw + i * KSTR] = pk2(vr[i], vr[8 + i]);
        }
        __syncthreads();   // A: drains the LDS writes; vm queue is empty here

        // ---- issue tile it+2 global loads (full compute phase to land) ----
        if (it + 2 < nt) {
            const float* kp = kgp + (it + 2) * 4096;
            const float* vp = vgp + (it + 2) * 4096;
            #pragma unroll
            for (int i = 0; i < 4; ++i) *(float4*)&kr[4 * i] = *(const float4*)(kp + 4 * i);
            *(float4*)&vr[0]  = *(const float4*)(vp);
            *(float4*)&vr[4]  = *(const float4*)(vp + 4);
            *(float4*)&vr[8]  = *(const float4*)(vp + D_);
            *(float4*)&vr[12] = *(const float4*)(vp + D_ + 4);
        }
        const float4 bt0 = *(const float4*)(bp + (it << 6));
        const float4 bt1 = *(const float4*)(bp + (it << 6) + 4);

        // ---- fragment ds_reads ----
        bf16x8 ka[2][2], va[4];
        #pragma unroll
        for (int mb = 0; mb < 2; ++mb)
            #pragma unroll
            for (int h = 0; h < 2; ++h)
                ka[mb][h] = *(const bf16x8*)&smem[kcb + aoff[mb][h]];
        #pragma unroll
        for (int mb = 0; mb < 4; ++mb) va[mb] = *(const bf16x8*)&smem[vcb + voff[mb]];

        // ---- QK: S^T = K_half · Qeff^T ----
        const f32x4 zz = {0, 0, 0, 0};
        f32x4 acc[2][2];
        #pragma unroll
        for (int mb = 0; mb < 2; ++mb)
            #pragma unroll
            for (int ng = 0; ng < 2; ++ng) {
                f32x4 a = __builtin_amdgcn_mfma_f32_16x16x32_bf16(ka[mb][0], qb[ng][0], zz, 0, 0, 0);
                acc[mb][ng] = __builtin_amdgcn_mfma_f32_16x16x32_bf16(ka[mb][1], qb[ng][1], a, 0, 0, 0);
            }

        const float btf[8] = {bt0.x * LOG2E, bt0.y * LOG2E, bt0.z * LOG2E, bt0.w * LOG2E,
                              bt1.x * LOG2E, bt1.y * LOG2E, bt1.z * LOG2E, bt1.w * LOG2E};
        const bool dm = (it == qt);
        const int kk = (it << 6) + kbase;

        // ---- fixed-max softmax + pack P (B-layout per lane) ----
        union { unsigned u[4]; bf16x8 v; } pf[2];
        #pragma unroll
        for (int ng = 0; ng < 2; ++ng) {
            const int qr = q0 + (qh << 5) + (ng << 4) + n_l;
            float p[8];
            float lacc = 0.0f;
            #pragma unroll
            for (int j = 0; j < 8; ++j) {
                const int mb = j >> 2, r = j & 3;
                float sv = fmaf(acc[mb][ng][r], KSC, btf[j]);
                if (dm) {
                    const int key = kk + j;
                    if (!((key < qr) || (qr == 0 && key == 0))) sv = -1.0e30f;
                }
                p[j] = __builtin_amdgcn_exp2f(sv);
                lacc += p[j];
            }
            l[ng] += lacc;
            pf[ng].u[0] = pk2(p[0], p[1]);
            pf[ng].u[1] = pk2(p[2], p[3]);
            pf[ng].u[2] = pk2(p[4], p[5]);
            pf[ng].u[3] = pk2(p[6], p[7]);
        }

        // ---- PV: O^T += V^T_half · P^T ----
        #pragma unroll
        for (int mb = 0; mb < 4; ++mb)
            #pragma unroll
            for (int ng = 0; ng < 2; ++ng)
                o[mb][ng] = __builtin_amdgcn_mfma_f32_16x16x32_bf16(va[mb], pf[ng].v, o[mb][ng], 0, 0, 0);

        __syncthreads();   // B: all frag reads done before next iter's writes; t+2 loads landed
    }

    // ---- epilogue: combine kh halves, normalize, store ----
    #pragma unroll
    for (int ng = 0; ng < 2; ++ng) {
        l[ng] += __shfl_xor(l[ng], 16);
        l[ng] += __shfl_xor(l[ng], 32);
    }
    float* opub = (float*)smem;          // 64 x 68 floats
    float* lred = opub + 4352;           // 64 floats
    if (kh == 0) {
        #pragma unroll
        for (int ng = 0; ng < 2; ++ng) {
            const int row = (qh << 5) + (ng << 4) + n_l;
            #pragma unroll
            for (int mb = 0; mb < 4; ++mb)
                *(float4*)&opub[row * 68 + (mb << 4) + (qd << 2)] =
                    make_float4(o[mb][ng][0], o[mb][ng][1], o[mb][ng][2], o[mb][ng][3]);
            if (qd == 0) lred[row] = l[ng];
        }
    }
    __syncthreads();
    if (kh == 1) {
        #pragma unroll
        for (int ng = 0; ng < 2; ++ng) {
            const int row = (qh << 5) + (ng << 4) + n_l;
            const float inv = 1.0f / (l[ng] + lred[row]);
            float* op = out + ((size_t)bh * S_ + q0 + row) * D_ + (qd << 2);
            #pragma unroll
            for (int mb = 0; mb < 4; ++mb) {
                float4 pv = *(float4*)&opub[row * 68 + (mb << 4) + (qd << 2)];
                *(float4*)(op + (mb << 4)) =
                    make_float4((o[mb][ng][0] + pv.x) * inv, (o[mb][ng][1] + pv.y) * inv,
                                (o[mb][ng][2] + pv.z) * inv, (o[mb][ng][3] + pv.w) * inv);
            }
        }
    }
}

extern "C" void kernel_launch(void* const* d_in, const int* in_sizes, int n_in,
                              void* d_out, int out_size, void* d_ws, size_t ws_size,
                              hipStream_t stream) {
    const float* Q    = (const float*)d_in[0];
    const float* K    = (const float*)d_in[1];
    const float* V    = (const float*)d_in[2];
    const float* beta = (const float*)d_in[3];
    // d_in[4]: causal mask (deterministic triu) — handled analytically in-kernel.
    float* out = (float*)d_out;

    attn5<<<dim3(512), dim3(256), 0, stream>>>(Q, K, V, beta, out);
}

// Round 6
// 128.173 us; speedup vs baseline: 1.0452x; 1.0452x over previous
//
#include <hip/hip_runtime.h>

// DotProductAttention reduced form (verified rounds 1-5, absmax 0.0156):
//   Qeff[q] = 0.7*Q[q-1] + Q[q] + 0.7*Q[q+1]  (zero pad at edges)
//   out[q]  = softmax_{k <= max(q-1,0)}( Qeff[q]·K[k]/8 + beta[k] ) @ V
// Round 6: barrier-free K-loop. K and V^T are pre-converted to bf16 in d_ws by two
// helper kernels; MFMA fragments are then DIRECT 16B global loads (L2-resident,
// 2 heads pinned per XCD) -- no LDS staging, no packing, no per-tile barriers.
// Wave = (key-half kh x 32-q strip sg); block = 4 waves on one 64-q tile, runs
// q-tile pair (j, 31-j) -> exactly 33 tiles per block (perfect balance).
// Permuted key->M-row keeps S^T C-frag == PV B-frag (P never leaves registers).
// Fixed-max softmax (scores bounded ~8.5; exp2 fp32-safe; partials additive).

typedef short bf16x8 __attribute__((ext_vector_type(8)));
typedef float f32x4  __attribute__((ext_vector_type(4)));

constexpr int S_ = 2048;
constexpr int D_ = 64;
constexpr float LOG2E = 1.44269504088896341f;
constexpr float KSC = 0.125f * LOG2E;   // 1/sqrt(64), log2 domain

// pack two fp32 -> dword of 2 bf16 (round-half-up), lo in low 16
__device__ __forceinline__ unsigned pk2(float lo, float hi) {
    union { float f; unsigned u; } a, b;
    a.f = lo; b.f = hi;
    return __builtin_amdgcn_perm(b.u + 0x8000u, a.u + 0x8000u, 0x07060302u);
}

// ---- K fp32 -> bf16, layout-preserving ----
__global__ __launch_bounds__(256)
void cvt_k(const float* __restrict__ K, unsigned short* __restrict__ Kbf)
{
    const size_t i = ((size_t)blockIdx.x * 256 + threadIdx.x) * 8;
    float4 a = *(const float4*)(K + i);
    float4 b = *(const float4*)(K + i + 4);
    *(uint4*)(Kbf + i) = make_uint4(pk2(a.x, a.y), pk2(a.z, a.w),
                                    pk2(b.x, b.y), pk2(b.z, b.w));
}

// ---- V fp32 [h][key][d] -> V^T bf16 [h][d][key] (64x64 LDS tile transpose) ----
__global__ __launch_bounds__(256)
void cvt_v(const float* __restrict__ V, unsigned short* __restrict__ Vt)
{
    __shared__ float T[64][65];
    const int k0 = blockIdx.x << 6;
    const int hd = blockIdx.y;
    const int t = threadIdx.x;
    {
        const int ky = t >> 2, dc = (t & 3) << 4;
        const float* vp = V + (((size_t)hd * S_) + k0 + ky) * D_ + dc;
        #pragma unroll
        for (int i = 0; i < 4; ++i) {
            float4 v4 = *(const float4*)(vp + 4 * i);
            T[ky][dc + 4 * i + 0] = v4.x;
            T[ky][dc + 4 * i + 1] = v4.y;
            T[ky][dc + 4 * i + 2] = v4.z;
            T[ky][dc + 4 * i + 3] = v4.w;
        }
    }
    __syncthreads();
    {
        const int d = t >> 2, kc = (t & 3) << 4;
        unsigned w[8];
        #pragma unroll
        for (int j = 0; j < 8; ++j)
            w[j] = pk2(T[kc + 2 * j][d], T[kc + 2 * j + 1][d]);
        unsigned short* op = Vt + ((size_t)hd * D_ + d) * S_ + k0 + kc;
        *(uint4*)(op)     = make_uint4(w[0], w[1], w[2], w[3]);
        *(uint4*)(op + 8) = make_uint4(w[4], w[5], w[6], w[7]);
    }
}

__global__ __launch_bounds__(256, 2)
void attn6(const float* __restrict__ Q, const float* __restrict__ beta,
           const unsigned short* __restrict__ Kbf, const unsigned short* __restrict__ Vt,
           float* __restrict__ out)
{
    __shared__ float opub[2][32][68];
    __shared__ float lred[2][32];

    const int bid = blockIdx.x;
    const int hd = bid & 15;          // head pinned to XCD hd&7 (2 heads/XCD, L2-resident K/V)
    const int pr = bid >> 4;          // pair index 0..15

    const float* Qh = Q + (size_t)hd * S_ * D_;
    const unsigned short* Kh = Kbf + (size_t)hd * S_ * D_;
    const unsigned short* Vh = Vt + (size_t)hd * D_ * S_;

    const int t = threadIdx.x, lane = t & 63;
    const int wv = t >> 6, kh = wv & 1, sg = wv >> 1;
    const int n_l = lane & 15, qd = lane >> 4;
    const int qdo = qd << 3;

    // permuted key->M-row mapping (within this wave's 32-key half)
    int krow[2];
    krow[0] = (kh << 5) + ((n_l >> 2) << 3) + (n_l & 3);
    krow[1] = krow[0] + 4;
    int dmb[4];
    #pragma unroll
    for (int mb = 0; mb < 4; ++mb) dmb[mb] = (mb << 4) + n_l;
    const int kvo = (kh << 5) + qdo;   // this lane's key offset within a tile

    for (int p = 0; p < 2; ++p) {
        const int j = p ? (31 - pr) : pr;
        const int q0 = j << 6;
        const int nt = j + 1;
        const int qbase = q0 + (sg << 5);

        auto ld = [&](int tile, bf16x8 (&ka)[2][2], bf16x8 (&vb)[4], float (&bt)[8]) {
            const unsigned short* kp = Kh + (size_t)(tile << 6) * D_;
            #pragma unroll
            for (int mb = 0; mb < 2; ++mb)
                #pragma unroll
                for (int hh = 0; hh < 2; ++hh)
                    ka[mb][hh] = *(const bf16x8*)(kp + krow[mb] * D_ + (hh << 5) + qdo);
            const unsigned short* vp = Vh + (tile << 6) + kvo;
            #pragma unroll
            for (int mb = 0; mb < 4; ++mb)
                vb[mb] = *(const bf16x8*)(vp + (size_t)dmb[mb] * S_);
            const float* bp = beta + (tile << 6) + kvo;
            float4 b0 = *(const float4*)(bp);
            float4 b1 = *(const float4*)(bp + 4);
            bt[0] = b0.x * LOG2E; bt[1] = b0.y * LOG2E;
            bt[2] = b0.z * LOG2E; bt[3] = b0.w * LOG2E;
            bt[4] = b1.x * LOG2E; bt[5] = b1.y * LOG2E;
            bt[6] = b1.z * LOG2E; bt[7] = b1.w * LOG2E;
        };

        // ---- issue tile-0 fragment loads before computing Qeff (overlap) ----
        bf16x8 kaA[2][2], vbA[4]; float btA[8];
        bf16x8 kaB[2][2], vbB[4]; float btB[8];
        ld(0, kaA, vbA, btA);

        // ---- Qeff B-fragments straight from global fp32 Q (per wave, no LDS) ----
        bf16x8 qb[2][2];
        #pragma unroll
        for (int ng = 0; ng < 2; ++ng) {
            const int q = qbase + (ng << 4) + n_l;
            const float wp = (q > 0) ? 0.7f : 0.0f;
            const float wn = (q + 1 < S_) ? 0.7f : 0.0f;
            const float* qc = Qh + (size_t)q * D_;
            const float* qpp = qc - ((q > 0) ? D_ : 0);
            const float* qnn = qc + ((q + 1 < S_) ? D_ : 0);
            #pragma unroll
            for (int hh = 0; hh < 2; ++hh) {
                const int d0 = (hh << 5) + qdo;
                float4 c0 = *(const float4*)(qc + d0),  c1 = *(const float4*)(qc + d0 + 4);
                float4 p0 = *(const float4*)(qpp + d0), p1 = *(const float4*)(qpp + d0 + 4);
                float4 n0 = *(const float4*)(qnn + d0), n1 = *(const float4*)(qnn + d0 + 4);
                float e0 = fmaf(wn, n0.x, fmaf(wp, p0.x, c0.x));
                float e1 = fmaf(wn, n0.y, fmaf(wp, p0.y, c0.y));
                float e2 = fmaf(wn, n0.z, fmaf(wp, p0.z, c0.z));
                float e3 = fmaf(wn, n0.w, fmaf(wp, p0.w, c0.w));
                float e4 = fmaf(wn, n1.x, fmaf(wp, p1.x, c1.x));
                float e5 = fmaf(wn, n1.y, fmaf(wp, p1.y, c1.y));
                float e6 = fmaf(wn, n1.z, fmaf(wp, p1.z, c1.z));
                float e7 = fmaf(wn, n1.w, fmaf(wp, p1.w, c1.w));
                union { unsigned u[4]; bf16x8 v; } qu;
                qu.u[0] = pk2(e0, e1); qu.u[1] = pk2(e2, e3);
                qu.u[2] = pk2(e4, e5); qu.u[3] = pk2(e6, e7);
                qb[ng][hh] = qu.v;
            }
        }

        f32x4 o[4][2];
        float l[2] = {0.0f, 0.0f};
        #pragma unroll
        for (int mb = 0; mb < 4; ++mb)
            #pragma unroll
            for (int ng = 0; ng < 2; ++ng) o[mb][ng] = (f32x4){0, 0, 0, 0};

        auto comp = [&](int tile, bf16x8 (&ka)[2][2], bf16x8 (&vb)[4], float (&bt)[8]) {
            const f32x4 zz = {0, 0, 0, 0};
            f32x4 acc[2][2];
            #pragma unroll
            for (int mb = 0; mb < 2; ++mb)
                #pragma unroll
                for (int ng = 0; ng < 2; ++ng) {
                    f32x4 a = __builtin_amdgcn_mfma_f32_16x16x32_bf16(ka[mb][0], qb[ng][0], zz, 0, 0, 0);
                    acc[mb][ng] = __builtin_amdgcn_mfma_f32_16x16x32_bf16(ka[mb][1], qb[ng][1], a, 0, 0, 0);
                }
            const bool dm = (tile == nt - 1);
            const int kk = (tile << 6) + kvo;
            union { unsigned u[4]; bf16x8 v; } pf[2];
            #pragma unroll
            for (int ng = 0; ng < 2; ++ng) {
                const int qr = qbase + (ng << 4) + n_l;
                float pv[8];
                float la = 0.0f;
                #pragma unroll
                for (int jj = 0; jj < 8; ++jj) {
                    const int mb = jj >> 2, r = jj & 3;
                    float sv = fmaf(acc[mb][ng][r], KSC, bt[jj]);
                    if (dm) {
                        const int key = kk + jj;
                        if (!((key < qr) || (qr == 0 && key == 0))) sv = -1.0e30f;
                    }
                    pv[jj] = __builtin_amdgcn_exp2f(sv);
                    la += pv[jj];
                }
                l[ng] += la;
                pf[ng].u[0] = pk2(pv[0], pv[1]);
                pf[ng].u[1] = pk2(pv[2], pv[3]);
                pf[ng].u[2] = pk2(pv[4], pv[5]);
                pf[ng].u[3] = pk2(pv[6], pv[7]);
            }
            #pragma unroll
            for (int mb = 0; mb < 4; ++mb)
                #pragma unroll
                for (int ng = 0; ng < 2; ++ng)
                    o[mb][ng] = __builtin_amdgcn_mfma_f32_16x16x32_bf16(vb[mb], pf[ng].v, o[mb][ng], 0, 0, 0);
        };

        // ---- barrier-free software-pipelined K-loop (2 frag sets) ----
        int it = 0;
        for (; it + 2 <= nt; it += 2) {
            ld(it + 1, kaB, vbB, btB);
            comp(it, kaA, vbA, btA);
            if (it + 2 < nt) ld(it + 2, kaA, vbA, btA);
            comp(it + 1, kaB, vbB, btB);
        }
        if (it < nt) comp(it, kaA, vbA, btA);

        // ---- epilogue: quad-reduce l, combine kh halves via LDS, store ----
        #pragma unroll
        for (int ng = 0; ng < 2; ++ng) {
            l[ng] += __shfl_xor(l[ng], 16);
            l[ng] += __shfl_xor(l[ng], 32);
        }
        __syncthreads();   // also orders vs previous pass's combine reads
        if (kh == 0) {
            #pragma unroll
            for (int ng = 0; ng < 2; ++ng) {
                const int row = (ng << 4) + n_l;
                #pragma unroll
                for (int mb = 0; mb < 4; ++mb)
                    *(float4*)&opub[sg][row][(mb << 4) + (qd << 2)] =
                        make_float4(o[mb][ng][0], o[mb][ng][1], o[mb][ng][2], o[mb][ng][3]);
                if (qd == 0) lred[sg][row] = l[ng];
            }
        }
        __syncthreads();
        if (kh == 1) {
            #pragma unroll
            for (int ng = 0; ng < 2; ++ng) {
                const int row = (ng << 4) + n_l;
                const float inv = 1.0f / (l[ng] + lred[sg][row]);
                float* op = out + ((size_t)hd * S_ + qbase + row) * D_ + (qd << 2);
                #pragma unroll
                for (int mb = 0; mb < 4; ++mb) {
                    float4 pv = *(float4*)&opub[sg][row][(mb << 4) + (qd << 2)];
                    *(float4*)(op + (mb << 4)) =
                        make_float4((o[mb][ng][0] + pv.x) * inv, (o[mb][ng][1] + pv.y) * inv,
                                    (o[mb][ng][2] + pv.z) * inv, (o[mb][ng][3] + pv.w) * inv);
                }
            }
        }
    }
}

extern "C" void kernel_launch(void* const* d_in, const int* in_sizes, int n_in,
                              void* d_out, int out_size, void* d_ws, size_t ws_size,
                              hipStream_t stream) {
    const float* Q    = (const float*)d_in[0];
    const float* K    = (const float*)d_in[1];
    const float* V    = (const float*)d_in[2];
    const float* beta = (const float*)d_in[3];
    // d_in[4]: causal mask (deterministic triu) — handled analytically in-kernel.
    float* out = (float*)d_out;

    unsigned short* Kbf = (unsigned short*)d_ws;                 // 16*2048*64 bf16 = 4 MB
    unsigned short* Vt  = Kbf + (size_t)16 * S_ * D_;            // 16*64*2048 bf16 = 4 MB

    cvt_k<<<dim3(1024), 256, 0, stream>>>(K, Kbf);
    cvt_v<<<dim3(32, 16), 256, 0, stream>>>(V, Vt);
    attn6<<<dim3(256), 256, 0, stream>>>(Q, beta, Kbf, Vt, out);
}

// Round 7
// 118.023 us; speedup vs baseline: 1.1350x; 1.0860x over previous
//
#include <hip/hip_runtime.h>

// DotProductAttention reduced form (verified rounds 1-6, absmax 0.0156):
//   Qeff[q] = 0.7*Q[q-1] + Q[q] + 0.7*Q[q+1]  (zero pad at edges)
//   out[q]  = softmax_{k <= max(q-1,0)}( Qeff[q]·K[k]/8 + beta[k] ) @ V
// Round 7: K/V^T pre-swizzled into EXACT MFMA-fragment order (F[hd][tile][frag]
// [lane][8]) so every K-loop load is a fully-coalesced global_load_dwordx4 at
// base+lane*16 (round 6's direct loads were 16x64B gathers). 8-wave blocks
// (kh half x 4 q-strips) -> 2 waves/SIMD. Barrier-free K-loop, 2-tile register
// pipeline with prefetch distance of 2 comp phases. Permuted key->M-row keeps
// S^T C-frag == PV B-frag (P never leaves registers). Fixed-max softmax.

typedef short bf16x8 __attribute__((ext_vector_type(8)));
typedef float f32x4  __attribute__((ext_vector_type(4)));

constexpr int S_ = 2048;
constexpr int D_ = 64;
constexpr float LOG2E = 1.44269504088896341f;
constexpr float KSC = 0.125f * LOG2E;   // 1/sqrt(64), log2 domain

// pack two fp32 -> dword of 2 bf16 (round-half-up), lo in low 16
__device__ __forceinline__ unsigned pk2(float lo, float hi) {
    union { float f; unsigned u; } a, b;
    a.f = lo; b.f = hi;
    return __builtin_amdgcn_perm(b.u + 0x8000u, a.u + 0x8000u, 0x07060302u);
}

// ---- fragment pre-swizzle: F[hd][tile][frag][lane][8] bf16 ----
// frag 0..7  = K A-frags  (kh*4 + mb*2 + hh): lane(n,qd) holds
//              K[key = 64t + 32kh + 8(n>>2) + (n&3) + 4mb][d = 32hh + 8qd .. +8]
// frag 8..15 = V^T A-frags (8 + kh*4 + mb): lane(n,qd) holds
//              V[key = 64t + 32kh + 8qd + j][d = 16mb + n], j = 0..7
__global__ __launch_bounds__(256)
void cvt_frag(const float* __restrict__ K, const float* __restrict__ V,
              unsigned short* __restrict__ F)
{
    const int tid  = blockIdx.x * 256 + threadIdx.x;
    const int lane = tid & 63;
    const int frag = (tid >> 6) & 15;
    const int tt   = (tid >> 10) & 31;
    const int hd   = tid >> 15;
    const int n_l = lane & 15, qd = lane >> 4;
    unsigned w[4];
    if (frag < 8) {
        const int kh = frag >> 2, mb = (frag >> 1) & 1, hh = frag & 1;
        const int key = tt * 64 + kh * 32 + ((n_l >> 2) << 3) + (n_l & 3) + mb * 4;
        const int d0  = hh * 32 + qd * 8;
        const float* src = K + (size_t)(hd * S_ + key) * D_ + d0;
        float4 a = *(const float4*)src;
        float4 b = *(const float4*)(src + 4);
        w[0] = pk2(a.x, a.y); w[1] = pk2(a.z, a.w);
        w[2] = pk2(b.x, b.y); w[3] = pk2(b.z, b.w);
    } else {
        const int kh = (frag >> 2) & 1, mb = frag & 3;
        const int key0 = tt * 64 + kh * 32 + qd * 8;
        const int d = mb * 16 + n_l;
        const float* src = V + (size_t)(hd * S_ + key0) * D_ + d;
        float e[8];
        #pragma unroll
        for (int j = 0; j < 8; ++j) e[j] = src[j * D_];
        w[0] = pk2(e[0], e[1]); w[1] = pk2(e[2], e[3]);
        w[2] = pk2(e[4], e[5]); w[3] = pk2(e[6], e[7]);
    }
    *(uint4*)(F + (size_t)tid * 8) = make_uint4(w[0], w[1], w[2], w[3]);
}

__global__ __launch_bounds__(512, 2)
void attn7(const float* __restrict__ Q, const float* __restrict__ beta,
           const unsigned short* __restrict__ F, float* __restrict__ out)
{
    __shared__ float opub[4][16][68];
    __shared__ float lred[4][16];

    const int bid = blockIdx.x;
    const int hd = bid & 15;          // head pinned to XCD bid&7 (2 heads/XCD)
    const int pr = bid >> 4;          // pair index 0..15 -> q-tiles (pr, 31-pr)

    const float* Qh = Q + (size_t)hd * S_ * D_;
    const unsigned short* Fh = F + (size_t)hd * 32 * 16 * 512;

    const int t = threadIdx.x, lane = t & 63;
    const int wv = t >> 6, kh = wv & 1, sg = wv >> 1;
    const int n_l = lane & 15, qd = lane >> 4;

    // fragment offsets (ushort) within one tile's 8192-ushort block
    const int lo = lane * 8;
    int kfo[2][2], vfo[4];
    #pragma unroll
    for (int mb = 0; mb < 2; ++mb)
        #pragma unroll
        for (int hh = 0; hh < 2; ++hh)
            kfo[mb][hh] = ((kh << 2) | (mb << 1) | hh) * 512 + lo;
    #pragma unroll
    for (int mb = 0; mb < 4; ++mb)
        vfo[mb] = (8 + (kh << 2) + mb) * 512 + lo;

    const int kvo = (kh << 5) + (qd << 3);   // lane's key offset within a tile
    const float* bp = beta + kvo;

    for (int p = 0; p < 2; ++p) {
        const int j = p ? (31 - pr) : pr;
        const int q0 = j << 6;
        const int nt = j + 1;
        const int qbase = q0 + (sg << 4);
        const int qr = qbase + n_l;          // this lane's q row

        auto ld = [&](int tile, bf16x8 (&ka)[2][2], bf16x8 (&vb)[4], float (&bt)[8]) {
            const unsigned short* fp = Fh + (size_t)tile * 8192;
            ka[0][0] = *(const bf16x8*)(fp + kfo[0][0]);
            ka[0][1] = *(const bf16x8*)(fp + kfo[0][1]);
            ka[1][0] = *(const bf16x8*)(fp + kfo[1][0]);
            ka[1][1] = *(const bf16x8*)(fp + kfo[1][1]);
            #pragma unroll
            for (int mb = 0; mb < 4; ++mb)
                vb[mb] = *(const bf16x8*)(fp + vfo[mb]);
            const float* bq = bp + (tile << 6);
            float4 b0 = *(const float4*)(bq);
            float4 b1 = *(const float4*)(bq + 4);
            bt[0] = b0.x * LOG2E; bt[1] = b0.y * LOG2E;
            bt[2] = b0.z * LOG2E; bt[3] = b0.w * LOG2E;
            bt[4] = b1.x * LOG2E; bt[5] = b1.y * LOG2E;
            bt[6] = b1.z * LOG2E; bt[7] = b1.w * LOG2E;
        };

        // ---- issue tile-0/1 fragment loads before computing Qeff (overlap) ----
        bf16x8 kaA[2][2], vbA[4]; float btA[8];
        bf16x8 kaB[2][2], vbB[4]; float btB[8];
        ld(0, kaA, vbA, btA);
        if (nt > 1) ld(1, kaB, vbB, btB);

        // ---- Qeff B-fragments straight from global fp32 Q (one q-row per lane) ----
        bf16x8 qb[2];
        {
            const float wp = (qr > 0) ? 0.7f : 0.0f;
            const float wn = (qr + 1 < S_) ? 0.7f : 0.0f;
            const float* qc = Qh + (size_t)qr * D_;
            const float* qpp = qc - ((qr > 0) ? D_ : 0);
            const float* qnn = qc + ((qr + 1 < S_) ? D_ : 0);
            #pragma unroll
            for (int hh = 0; hh < 2; ++hh) {
                const int d0 = (hh << 5) + (qd << 3);
                float4 c0 = *(const float4*)(qc + d0),  c1 = *(const float4*)(qc + d0 + 4);
                float4 p0 = *(const float4*)(qpp + d0), p1 = *(const float4*)(qpp + d0 + 4);
                float4 n0 = *(const float4*)(qnn + d0), n1 = *(const float4*)(qnn + d0 + 4);
                float e0 = fmaf(wn, n0.x, fmaf(wp, p0.x, c0.x));
                float e1 = fmaf(wn, n0.y, fmaf(wp, p0.y, c0.y));
                float e2 = fmaf(wn, n0.z, fmaf(wp, p0.z, c0.z));
                float e3 = fmaf(wn, n0.w, fmaf(wp, p0.w, c0.w));
                float e4 = fmaf(wn, n1.x, fmaf(wp, p1.x, c1.x));
                float e5 = fmaf(wn, n1.y, fmaf(wp, p1.y, c1.y));
                float e6 = fmaf(wn, n1.z, fmaf(wp, p1.z, c1.z));
                float e7 = fmaf(wn, n1.w, fmaf(wp, p1.w, c1.w));
                union { unsigned u[4]; bf16x8 v; } qu;
                qu.u[0] = pk2(e0, e1); qu.u[1] = pk2(e2, e3);
                qu.u[2] = pk2(e4, e5); qu.u[3] = pk2(e6, e7);
                qb[hh] = qu.v;
            }
        }

        f32x4 o[4];
        float l = 0.0f;
        #pragma unroll
        for (int mb = 0; mb < 4; ++mb) o[mb] = (f32x4){0, 0, 0, 0};

        auto comp = [&](int tile, bf16x8 (&ka)[2][2], bf16x8 (&vb)[4], float (&bt)[8]) {
            const f32x4 zz = {0, 0, 0, 0};
            f32x4 acc[2];
            #pragma unroll
            for (int mb = 0; mb < 2; ++mb) {
                f32x4 a = __builtin_amdgcn_mfma_f32_16x16x32_bf16(ka[mb][0], qb[0], zz, 0, 0, 0);
                acc[mb] = __builtin_amdgcn_mfma_f32_16x16x32_bf16(ka[mb][1], qb[1], a, 0, 0, 0);
            }
            const bool dm = (tile == nt - 1);
            const int kk = (tile << 6) + kvo;
            float pv[8];
            float la = 0.0f;
            #pragma unroll
            for (int jj = 0; jj < 8; ++jj) {
                const int mb = jj >> 2, r = jj & 3;
                float sv = fmaf(acc[mb][r], KSC, bt[jj]);
                if (dm) {
                    const int key = kk + jj;
                    if (!((key < qr) || (qr == 0 && key == 0))) sv = -1.0e30f;
                }
                pv[jj] = __builtin_amdgcn_exp2f(sv);
                la += pv[jj];
            }
            l += la;
            union { unsigned u[4]; bf16x8 v; } pf;
            pf.u[0] = pk2(pv[0], pv[1]);
            pf.u[1] = pk2(pv[2], pv[3]);
            pf.u[2] = pk2(pv[4], pv[5]);
            pf.u[3] = pk2(pv[6], pv[7]);
            #pragma unroll
            for (int mb = 0; mb < 4; ++mb)
                o[mb] = __builtin_amdgcn_mfma_f32_16x16x32_bf16(vb[mb], pf.v, o[mb], 0, 0, 0);
        };

        // ---- barrier-free pipelined K-loop (prefetch distance = 2 comp phases) ----
        int it = 0;
        for (; it + 2 <= nt; it += 2) {
            comp(it, kaA, vbA, btA);
            if (it + 2 < nt) ld(it + 2, kaA, vbA, btA);
            comp(it + 1, kaB, vbB, btB);
            if (it + 3 < nt) ld(it + 3, kaB, vbB, btB);
        }
        if (it < nt) comp(it, kaA, vbA, btA);

        // ---- epilogue: quad-reduce l, combine kh halves via LDS, store ----
        l += __shfl_xor(l, 16);
        l += __shfl_xor(l, 32);
        __syncthreads();   // orders vs previous pass's combine reads
        if (kh == 0) {
            #pragma unroll
            for (int mb = 0; mb < 4; ++mb)
                *(float4*)&opub[sg][n_l][(mb << 4) + (qd << 2)] =
                    make_float4(o[mb][0], o[mb][1], o[mb][2], o[mb][3]);
            if (qd == 0) lred[sg][n_l] = l;
        }
        __syncthreads();
        if (kh == 1) {
            const float inv = 1.0f / (l + lred[sg][n_l]);
            float* op = out + ((size_t)hd * S_ + qr) * D_ + (qd << 2);
            #pragma unroll
            for (int mb = 0; mb < 4; ++mb) {
                float4 pv = *(float4*)&opub[sg][n_l][(mb << 4) + (qd << 2)];
                *(float4*)(op + (mb << 4)) =
                    make_float4((o[mb][0] + pv.x) * inv, (o[mb][1] + pv.y) * inv,
                                (o[mb][2] + pv.z) * inv, (o[mb][3] + pv.w) * inv);
            }
        }
    }
}

extern "C" void kernel_launch(void* const* d_in, const int* in_sizes, int n_in,
                              void* d_out, int out_size, void* d_ws, size_t ws_size,
                              hipStream_t stream) {
    const float* Q    = (const float*)d_in[0];
    const float* K    = (const float*)d_in[1];
    const float* V    = (const float*)d_in[2];
    const float* beta = (const float*)d_in[3];
    // d_in[4]: causal mask (deterministic triu) — handled analytically in-kernel.
    float* out = (float*)d_out;

    unsigned short* F = (unsigned short*)d_ws;   // 16 hd x 32 t x 16 frag x 512 = 8 MB

    cvt_frag<<<dim3(2048), 256, 0, stream>>>(K, V, F);
    attn7<<<dim3(256), 512, 0, stream>>>(Q, beta, F, out);
}